// Round 1
// baseline (1510.090 us; speedup 1.0000x reference)
//
#include <hip/hip_runtime.h>

// CCL 8-connectivity on 4096x4096 binary image (prob > 0.5).
// Output: int32 labels, label = (min linear index in component) + 1, bg = 0.
// Union-find with union-by-min-index => root == min index of component.

constexpr int HH = 4096;
constexpr int WW = 4096;
constexpr int NPIX = HH * WW;

// ---------------------------------------------------------------- init ----
__global__ void ccl_init(const float* __restrict__ prob, int* __restrict__ P) {
    int i = (blockIdx.x * blockDim.x + threadIdx.x) * 4;
    float4 v = *reinterpret_cast<const float4*>(prob + i);
    int4 o;
    o.x = (v.x > 0.5f) ? i     : -1;
    o.y = (v.y > 0.5f) ? i + 1 : -1;
    o.z = (v.z > 0.5f) ? i + 2 : -1;
    o.w = (v.w > 0.5f) ? i + 3 : -1;
    *reinterpret_cast<int4*>(P + i) = o;
}

// ------------------------------------------------------------ union-find --
// All concurrent writes to P during the merge phase are atomicMin => values
// are monotonically decreasing and always point to a node in the same
// component. Hence every race is benign.
__device__ __forceinline__ int find_root(int* P, int x) {
    while (true) {
        int p = P[x];
        if (p == x) return x;
        int gp = P[p];
        if (gp == p) return p;
        atomicMin(&P[x], gp);   // path halving (race-safe: monotone)
        x = gp;
    }
}

__device__ __forceinline__ void unite(int* P, int a, int b) {
    while (true) {
        a = find_root(P, a);
        b = find_root(P, b);
        if (a == b) return;
        if (a > b) { int t = a; a = b; b = t; }
        int old = atomicMin(&P[b], a);  // link larger root to smaller
        if (old == b) return;           // b was still a root: linked, done
        b = old;                        // root moved concurrently: retry
    }
}

// --------------------------------------------------------------- merge ----
__global__ void ccl_merge(int* __restrict__ P) {
    int c = blockIdx.x * blockDim.x + threadIdx.x;
    int r = blockIdx.y * blockDim.y + threadIdx.y;
    int i = r * WW + c;
    if (P[i] < 0) return;                       // background
    if (c > 0 && P[i - 1] >= 0) unite(P, i, i - 1);           // W
    if (r > 0) {
        int j = i - WW;
        if (P[j] >= 0) {
            unite(P, i, j);                                   // N
            // NW/NE are transitively connected through N via the
            // horizontal links created in row r-1; skip them.
        } else {
            if (c > 0      && P[j - 1] >= 0) unite(P, i, j - 1);  // NW
            if (c < WW - 1 && P[j + 1] >= 0) unite(P, i, j + 1);  // NE
        }
    }
}

// ------------------------------------------------------------- compress ---
__global__ void ccl_compress(int* __restrict__ P) {
    int i = blockIdx.x * blockDim.x + threadIdx.x;
    int x = P[i];
    if (x < 0) return;
    while (true) {                 // chase to root (reads may see other
        int p = P[x];              // threads' compression writes — those are
        if (p == x) break;         // always true roots, still valid)
        x = p;
    }
    P[i] = x;
}

// -------------------------------------------------------------- convert ---
__global__ void ccl_convert(int* __restrict__ P) {
    int i = (blockIdx.x * blockDim.x + threadIdx.x) * 4;
    int4 v = *reinterpret_cast<const int4*>(P + i);
    v.x = (v.x < 0) ? 0 : v.x + 1;
    v.y = (v.y < 0) ? 0 : v.y + 1;
    v.z = (v.z < 0) ? 0 : v.z + 1;
    v.w = (v.w < 0) ? 0 : v.w + 1;
    *reinterpret_cast<int4*>(P + i) = v;
}

// ---------------------------------------------------------------- launch --
extern "C" void kernel_launch(void* const* d_in, const int* in_sizes, int n_in,
                              void* d_out, int out_size, void* d_ws, size_t ws_size,
                              hipStream_t stream) {
    const float* prob = (const float*)d_in[0];
    int* P = (int*)d_out;   // parent array lives in the output buffer

    ccl_init<<<dim3(NPIX / 4 / 256), dim3(256), 0, stream>>>(prob, P);

    dim3 bm(64, 4);
    dim3 gm(WW / 64, HH / 4);
    ccl_merge<<<gm, bm, 0, stream>>>(P);

    ccl_compress<<<dim3(NPIX / 256), dim3(256), 0, stream>>>(P);

    ccl_convert<<<dim3(NPIX / 4 / 256), dim3(256), 0, stream>>>(P);
}

// Round 2
// 415.212 us; speedup vs baseline: 3.6369x; 3.6369x over previous
//
#include <hip/hip_runtime.h>

// CCL 8-connectivity on 4096x4096 binary image (prob > 0.5).
// Output: int32 labels (as float-compat buffer), label = min linear index + 1, bg = 0.
//
// Strategy: block-local union-find in LDS per 64x64 tile (fast LDS atomics),
// then global union-find only across tile borders, then one fused
// resolve+convert pass writing to d_out. Parent array lives in d_ws.

constexpr int HH = 4096;
constexpr int WW = 4096;
constexpr int NPIX = HH * WW;
constexpr int TILE = 64;

// ---------------------------------------------------- global union-find ---
__device__ __forceinline__ int find_root_g(int* P, int x) {
    while (true) {
        int p = P[x];
        if (p == x) return x;
        int gp = P[p];
        if (gp == p) return p;
        atomicMin(&P[x], gp);   // path halving (monotone => race-safe)
        x = gp;
    }
}

__device__ __forceinline__ void unite_g(int* P, int a, int b) {
    while (true) {
        a = find_root_g(P, a);
        b = find_root_g(P, b);
        if (a == b) return;
        if (a > b) { int t = a; a = b; b = t; }
        int old = atomicMin(&P[b], a);
        if (old == b) return;
        b = old;
    }
}

// ------------------------------------------------------- LDS union-find ---
__device__ __forceinline__ int find_root_l(int* L, int x) {
    while (true) {
        int p = L[x];
        if (p == x) return x;
        int gp = L[p];
        if (gp == p) return p;
        atomicMin(&L[x], gp);
        x = gp;
    }
}

__device__ __forceinline__ void unite_l(int* L, int a, int b) {
    while (true) {
        a = find_root_l(L, a);
        b = find_root_l(L, b);
        if (a == b) return;
        if (a > b) { int t = a; a = b; b = t; }
        int old = atomicMin(&L[b], a);
        if (old == b) return;
        b = old;
    }
}

// ------------------------------------------------- local (per-tile) CCL ---
// Block = (64,4) threads; each thread handles 16 rows at its column.
__global__ __launch_bounds__(256) void ccl_local(const float* __restrict__ prob,
                                                 int* __restrict__ P) {
    __shared__ int L[TILE * TILE];
    const int tile_c = blockIdx.x * TILE;
    const int tile_r = blockIdx.y * TILE;
    const int tx = threadIdx.x;      // 0..63
    const int ty = threadIdx.y;      // 0..3

    // load threshold -> LDS parents
    #pragma unroll
    for (int k = 0; k < 16; ++k) {
        int lr = k * 4 + ty;
        int li = lr * TILE + tx;
        float v = prob[(tile_r + lr) * WW + tile_c + tx];
        L[li] = (v > 0.5f) ? li : -1;
    }
    __syncthreads();

    // in-tile merges (W, N; NW/NE only when N is background)
    #pragma unroll
    for (int k = 0; k < 16; ++k) {
        int lr = k * 4 + ty;
        int li = lr * TILE + tx;
        if (L[li] < 0) continue;
        if (tx > 0 && L[li - 1] >= 0) unite_l(L, li, li - 1);
        if (lr > 0) {
            int j = li - TILE;
            if (L[j] >= 0) {
                unite_l(L, li, j);
            } else {
                if (tx > 0        && L[j - 1] >= 0) unite_l(L, li, j - 1);
                if (tx < TILE - 1 && L[j + 1] >= 0) unite_l(L, li, j + 1);
            }
        }
    }
    __syncthreads();

    // flatten to tile root, write global parent
    #pragma unroll
    for (int k = 0; k < 16; ++k) {
        int lr = k * 4 + ty;
        int li = lr * TILE + tx;
        int gi = (tile_r + lr) * WW + tile_c + tx;
        int x = L[li];
        if (x < 0) { P[gi] = -1; continue; }
        while (true) { int p = L[x]; if (p == x) break; x = p; }
        P[gi] = (tile_r + (x >> 6)) * WW + tile_c + (x & 63);
    }
}

// ------------------------------------------------- cross-tile border fix --
// Horizontal tile boundaries: pixels in rows r = 64,128,... unite with the
// row above (N; NW/NE when N is background — transitive closure via the
// row-above horizontal links, which exist from local pass or border_v).
__global__ void ccl_border_h(int* __restrict__ P) {
    int c = blockIdx.x * blockDim.x + threadIdx.x;
    int r = (blockIdx.y + 1) * TILE;
    int i = r * WW + c;
    if (P[i] < 0) return;
    int j = i - WW;
    if (P[j] >= 0) {
        unite_g(P, i, j);
    } else {
        if (c > 0      && P[j - 1] >= 0) unite_g(P, i, j - 1);
        if (c < WW - 1 && P[j + 1] >= 0) unite_g(P, i, j + 1);
    }
}

// Vertical tile boundaries: pixels in cols c = 64,128,... unite W, NW, SW —
// covers all three cross-column adjacency families.
__global__ void ccl_border_v(int* __restrict__ P) {
    int r = blockIdx.x * blockDim.x + threadIdx.x;
    int c = (blockIdx.y + 1) * TILE;
    int i = r * WW + c;
    if (P[i] < 0) return;
    if (P[i - 1] >= 0) unite_g(P, i, i - 1);
    if (r > 0      && P[i - WW - 1] >= 0) unite_g(P, i, i - WW - 1);
    if (r < HH - 1 && P[i + WW - 1] >= 0) unite_g(P, i, i + WW - 1);
}

// ------------------------------------------ resolve + convert (to d_out) --
__device__ __forceinline__ int resolve1(const int* __restrict__ P, int x) {
    if (x < 0) return 0;
    while (true) { int p = P[x]; if (p == x) break; x = p; }
    return x + 1;
}

__global__ void ccl_final4(const int* __restrict__ P, int* __restrict__ out) {
    int i = (blockIdx.x * blockDim.x + threadIdx.x) * 4;
    int4 v = *reinterpret_cast<const int4*>(P + i);
    int4 o;
    o.x = resolve1(P, v.x);
    o.y = resolve1(P, v.y);
    o.z = resolve1(P, v.z);
    o.w = resolve1(P, v.w);
    *reinterpret_cast<int4*>(out + i) = o;
}

// ---------------------------- fallback path (P aliases d_out, no ws) ------
__global__ void ccl_compress(int* __restrict__ P) {
    int i = blockIdx.x * blockDim.x + threadIdx.x;
    int x = P[i];
    if (x < 0) return;
    while (true) { int p = P[x]; if (p == x) break; x = p; }
    P[i] = x;
}

__global__ void ccl_convert(int* __restrict__ P) {
    int i = (blockIdx.x * blockDim.x + threadIdx.x) * 4;
    int4 v = *reinterpret_cast<const int4*>(P + i);
    v.x = (v.x < 0) ? 0 : v.x + 1;
    v.y = (v.y < 0) ? 0 : v.y + 1;
    v.z = (v.z < 0) ? 0 : v.z + 1;
    v.w = (v.w < 0) ? 0 : v.w + 1;
    *reinterpret_cast<int4*>(P + i) = v;
}

// ---------------------------------------------------------------- launch --
extern "C" void kernel_launch(void* const* d_in, const int* in_sizes, int n_in,
                              void* d_out, int out_size, void* d_ws, size_t ws_size,
                              hipStream_t stream) {
    const float* prob = (const float*)d_in[0];
    const bool have_ws = ws_size >= (size_t)NPIX * sizeof(int);
    int* P = have_ws ? (int*)d_ws : (int*)d_out;

    // per-tile local CCL (also initializes every P entry)
    ccl_local<<<dim3(WW / TILE, HH / TILE), dim3(64, 4), 0, stream>>>(prob, P);

    // cross-tile merges (boundary pixels only)
    dim3 bb(256);
    dim3 gb(WW / 256, HH / TILE - 1);
    ccl_border_h<<<gb, bb, 0, stream>>>(P);
    ccl_border_v<<<dim3(HH / 256, WW / TILE - 1), bb, 0, stream>>>(P);

    if (have_ws) {
        ccl_final4<<<dim3(NPIX / 4 / 256), dim3(256), 0, stream>>>(P, (int*)d_out);
    } else {
        ccl_compress<<<dim3(NPIX / 256), dim3(256), 0, stream>>>(P);
        ccl_convert<<<dim3(NPIX / 4 / 256), dim3(256), 0, stream>>>(P);
    }
}

// Round 3
// 256.030 us; speedup vs baseline: 5.8981x; 1.6217x over previous
//
#include <hip/hip_runtime.h>
#include <limits.h>

// CCL 8-connectivity on 4096x4096 binary image (prob > 0.5).
// Output: int32 labels, label = (min linear index in component) + 1, bg = 0.
//
// Local phase: BKE 2x2-block union-find in LDS (1024 nodes per 64x64 tile;
// in 8-conn all fg pixels of a 2x2 block are mutually adjacent). Each tile
// component's root pixel is its min fg pixel (via LDS atomicMin aggregation),
// so cross-tile pixel-level union-by-min + final resolve yields min-index
// labels directly.

constexpr int HH = 4096;
constexpr int WW = 4096;
constexpr int NPIX = HH * WW;
constexpr int TILE = 64;
constexpr int BDIM = TILE / 2;        // 32 blocks per tile dim
constexpr int NBLK = BDIM * BDIM;     // 1024

// ---------------------------------------------------- global union-find ---
__device__ __forceinline__ int find_root_g(int* P, int x) {
    while (true) {
        int p = P[x];
        if (p == x) return x;
        int gp = P[p];
        if (gp == p) return p;
        atomicMin(&P[x], gp);   // path halving (monotone => race-safe)
        x = gp;
    }
}

__device__ __forceinline__ void unite_g(int* P, int a, int b) {
    while (true) {
        a = find_root_g(P, a);
        b = find_root_g(P, b);
        if (a == b) return;
        if (a > b) { int t = a; a = b; b = t; }
        int old = atomicMin(&P[b], a);
        if (old == b) return;
        b = old;
    }
}

// ------------------------------------------------------- LDS union-find ---
__device__ __forceinline__ int find_root_l(int* L, int x) {
    while (true) {
        int p = L[x];
        if (p == x) return x;
        int gp = L[p];
        if (gp == p) return p;
        atomicMin(&L[x], gp);
        x = gp;
    }
}

__device__ __forceinline__ void unite_l(int* L, int a, int b) {
    while (true) {
        a = find_root_l(L, a);
        b = find_root_l(L, b);
        if (a == b) return;
        if (a > b) { int t = a; a = b; b = t; }
        int old = atomicMin(&L[b], a);
        if (old == b) return;
        b = old;
    }
}

// ------------------------------------------- local (per-tile) BKE CCL -----
// Block masks: bit0=b00 (r,c), bit1=b01 (r,c+1), bit2=b10 (r+1,c), bit3=b11.
// Left col = 0x5, right col = 0xA, top row = 0x3, bottom row = 0xC.
__global__ __launch_bounds__(256) void ccl_local_bke(const float* __restrict__ prob,
                                                     int* __restrict__ P) {
    __shared__ int bmask[NBLK];
    __shared__ int parent[NBLK];
    __shared__ int minpix[NBLK];
    const int tile_c = blockIdx.x * TILE;
    const int tile_r = blockIdx.y * TILE;
    const int tid = threadIdx.x;

    int nib[4];
    #pragma unroll
    for (int k = 0; k < 4; ++k) {
        int b = tid + 256 * k;
        int i = b >> 5, j = b & 31;
        const float* rp = prob + (size_t)(tile_r + 2 * i) * WW + tile_c + 2 * j;
        float2 t = *reinterpret_cast<const float2*>(rp);
        float2 bo = *reinterpret_cast<const float2*>(rp + WW);
        int m = (t.x > 0.5f ? 1 : 0) | (t.y > 0.5f ? 2 : 0) |
                (bo.x > 0.5f ? 4 : 0) | (bo.y > 0.5f ? 8 : 0);
        nib[k] = m;
        bmask[b] = m;
        parent[b] = m ? b : -1;
        minpix[b] = INT_MAX;
    }
    __syncthreads();

    #pragma unroll
    for (int k = 0; k < 4; ++k) {
        int m = nib[k];
        if (!m) continue;
        int b = tid + 256 * k;
        int i = b >> 5, j = b & 31;
        if (j > 0 && (m & 0x5) && (bmask[b - 1] & 0xA)) unite_l(parent, b, b - 1);
        if (i > 0) {
            if ((m & 0x3) && (bmask[b - BDIM] & 0xC)) unite_l(parent, b, b - BDIM);
            if (j > 0        && (m & 0x1) && (bmask[b - BDIM - 1] & 0x8)) unite_l(parent, b, b - BDIM - 1);
            if (j < BDIM - 1 && (m & 0x2) && (bmask[b - BDIM + 1] & 0x4)) unite_l(parent, b, b - BDIM + 1);
        }
    }
    __syncthreads();

    int root[4];
    #pragma unroll
    for (int k = 0; k < 4; ++k) {
        int m = nib[k];
        if (!m) { root[k] = -1; continue; }
        int b = tid + 256 * k;
        int x = b;
        while (true) { int p = parent[x]; if (p == x) break; x = p; }
        root[k] = x;
        int i = b >> 5, j = b & 31;
        int gr = tile_r + 2 * i, gc = tile_c + 2 * j;
        int pm;
        if      (m & 1) pm = gr * WW + gc;
        else if (m & 2) pm = gr * WW + gc + 1;
        else if (m & 4) pm = (gr + 1) * WW + gc;
        else            pm = (gr + 1) * WW + gc + 1;
        atomicMin(&minpix[x], pm);
    }
    __syncthreads();

    #pragma unroll
    for (int k = 0; k < 4; ++k) {
        int b = tid + 256 * k;
        int i = b >> 5, j = b & 31;
        int gr = tile_r + 2 * i, gc = tile_c + 2 * j;
        int m = nib[k];
        int2 top = make_int2(-1, -1), bot = make_int2(-1, -1);
        if (m) {
            int lbl = minpix[root[k]];
            top.x = (m & 1) ? lbl : -1;
            top.y = (m & 2) ? lbl : -1;
            bot.x = (m & 4) ? lbl : -1;
            bot.y = (m & 8) ? lbl : -1;
        }
        *reinterpret_cast<int2*>(P + (size_t)gr * WW + gc) = top;
        *reinterpret_cast<int2*>(P + (size_t)(gr + 1) * WW + gc) = bot;
    }
}

// ------------------------------------------------- cross-tile border fix --
__global__ void ccl_border_h(int* __restrict__ P) {
    int c = blockIdx.x * blockDim.x + threadIdx.x;
    int r = (blockIdx.y + 1) * TILE;
    int i = r * WW + c;
    if (P[i] < 0) return;
    int j = i - WW;
    if (P[j] >= 0) {
        unite_g(P, i, j);     // NW/NE transitively covered via row-above links
    } else {
        if (c > 0      && P[j - 1] >= 0) unite_g(P, i, j - 1);
        if (c < WW - 1 && P[j + 1] >= 0) unite_g(P, i, j + 1);
    }
}

__global__ void ccl_border_v(int* __restrict__ P) {
    int r = blockIdx.x * blockDim.x + threadIdx.x;
    int c = (blockIdx.y + 1) * TILE;
    int i = r * WW + c;
    if (P[i] < 0) return;
    if (P[i - 1] >= 0) unite_g(P, i, i - 1);                      // W
    if (r > 0      && P[i - WW - 1] >= 0) unite_g(P, i, i - WW - 1);  // NW
    if (r < HH - 1 && P[i + WW - 1] >= 0) unite_g(P, i, i + WW - 1);  // SW
}

// ------------------------------------------ resolve + convert (to d_out) --
__device__ __forceinline__ int resolve_memo(const int* __restrict__ P, int x,
                                            int& ci, int& co) {
    if (x < 0) return 0;
    if (x == ci) return co;
    int r = x;
    while (true) { int p = P[r]; if (p == r) break; r = p; }
    ci = x; co = r + 1;
    return co;
}

__global__ void ccl_final4(const int* __restrict__ P, int* __restrict__ out) {
    int i = (blockIdx.x * blockDim.x + threadIdx.x) * 4;
    int4 v = *reinterpret_cast<const int4*>(P + i);
    int ci = -2, co = 0;
    int4 o;
    o.x = resolve_memo(P, v.x, ci, co);
    o.y = resolve_memo(P, v.y, ci, co);
    o.z = resolve_memo(P, v.z, ci, co);
    o.w = resolve_memo(P, v.w, ci, co);
    *reinterpret_cast<int4*>(out + i) = o;
}

// ---------------------------- fallback path (P aliases d_out, no ws) ------
__global__ void ccl_compress(int* __restrict__ P) {
    int i = blockIdx.x * blockDim.x + threadIdx.x;
    int x = P[i];
    if (x < 0) return;
    while (true) { int p = P[x]; if (p == x) break; x = p; }
    P[i] = x;
}

__global__ void ccl_convert(int* __restrict__ P) {
    int i = (blockIdx.x * blockDim.x + threadIdx.x) * 4;
    int4 v = *reinterpret_cast<const int4*>(P + i);
    v.x = (v.x < 0) ? 0 : v.x + 1;
    v.y = (v.y < 0) ? 0 : v.y + 1;
    v.z = (v.z < 0) ? 0 : v.z + 1;
    v.w = (v.w < 0) ? 0 : v.w + 1;
    *reinterpret_cast<int4*>(P + i) = v;
}

// ---------------------------------------------------------------- launch --
extern "C" void kernel_launch(void* const* d_in, const int* in_sizes, int n_in,
                              void* d_out, int out_size, void* d_ws, size_t ws_size,
                              hipStream_t stream) {
    const float* prob = (const float*)d_in[0];
    const bool have_ws = ws_size >= (size_t)NPIX * sizeof(int);
    int* P = have_ws ? (int*)d_ws : (int*)d_out;

    ccl_local_bke<<<dim3(WW / TILE, HH / TILE), dim3(256), 0, stream>>>(prob, P);

    dim3 bb(256);
    ccl_border_h<<<dim3(WW / 256, HH / TILE - 1), bb, 0, stream>>>(P);
    ccl_border_v<<<dim3(HH / 256, WW / TILE - 1), bb, 0, stream>>>(P);

    if (have_ws) {
        ccl_final4<<<dim3(NPIX / 4 / 256), dim3(256), 0, stream>>>(P, (int*)d_out);
    } else {
        ccl_compress<<<dim3(NPIX / 256), dim3(256), 0, stream>>>(P);
        ccl_convert<<<dim3(NPIX / 4 / 256), dim3(256), 0, stream>>>(P);
    }
}